// Round 3
// baseline (676.715 us; speedup 1.0000x reference)
//
#include <hip/hip_runtime.h>
#include <hip/hip_bf16.h>

#define B_   4
#define DENC 512
#define T_   200
#define DDEC 640
#define U_   100
#define H_   640
#define V_   1025
#define VPAD 1152   // 9 * 128

typedef float f32x4 __attribute__((ext_vector_type(4)));
typedef __bf16 bf16x8 __attribute__((ext_vector_type(8)));
typedef unsigned short u16x8 __attribute__((ext_vector_type(8)));

__device__ __forceinline__ float bf2f(unsigned short s) {
    return __uint_as_float(((unsigned)s) << 16);
}

// ---------------- K1: enc_proj[b,t,h] = bf16( sum_d enc[b,d,t]*W_enc[d,h] + b_enc[h] )
// no LDS, no barriers: block = (128 h) x (8 t); enc column loads are wave-uniform broadcasts
__global__ __launch_bounds__(128) void enc_proj_kernel(
    const float* __restrict__ enc, const float* __restrict__ W,
    const float* __restrict__ bias, __hip_bfloat16* __restrict__ out)
{
    int hc = blockIdx.x;              // 0..4
    int tg = blockIdx.y;              // 0..24
    int b  = blockIdx.z;
    int h  = hc * 128 + threadIdx.x;
    int t0 = tg * 8;
    const float* ec = enc + (size_t)b * DENC * T_ + t0;
    const float* Wc = W + h;
    float acc[8] = {0.f,0.f,0.f,0.f,0.f,0.f,0.f,0.f};
    #pragma unroll 8
    for (int d = 0; d < DENC; ++d) {
        float w = Wc[(size_t)d * H_];
        float4 e0 = *(const float4*)(ec + (size_t)d * T_);
        float4 e1 = *(const float4*)(ec + (size_t)d * T_ + 4);
        acc[0] += w * e0.x; acc[1] += w * e0.y; acc[2] += w * e0.z; acc[3] += w * e0.w;
        acc[4] += w * e1.x; acc[5] += w * e1.y; acc[6] += w * e1.z; acc[7] += w * e1.w;
    }
    float bb = bias[h];
    #pragma unroll
    for (int i = 0; i < 8; ++i)
        out[((size_t)b * T_ + t0 + i) * H_ + h] = __float2bfloat16(acc[i] + bb);
}

// ---------------- K2: dec_proj[b,u,h] = bf16( sum_d dec[b,d,u]*W_pred[d,h] + b_pred[h] )
__global__ __launch_bounds__(128) void dec_proj_kernel(
    const float* __restrict__ dec, const float* __restrict__ W,
    const float* __restrict__ bias, __hip_bfloat16* __restrict__ out)
{
    int hc = blockIdx.x;              // 0..4
    int ug = blockIdx.y;              // 0..24
    int b  = blockIdx.z;
    int h  = hc * 128 + threadIdx.x;
    int u0 = ug * 4;
    const float* dc = dec + (size_t)b * DDEC * U_ + u0;
    const float* Wc = W + h;
    float acc[4] = {0.f,0.f,0.f,0.f};
    #pragma unroll 8
    for (int d = 0; d < DDEC; ++d) {
        float w = Wc[(size_t)d * H_];
        float4 e0 = *(const float4*)(dc + (size_t)d * U_);
        acc[0] += w * e0.x; acc[1] += w * e0.y; acc[2] += w * e0.z; acc[3] += w * e0.w;
    }
    float bb = bias[h];
    #pragma unroll
    for (int i = 0; i < 4; ++i)
        out[((size_t)b * U_ + u0 + i) * H_ + h] = __float2bfloat16(acc[i] + bb);
}

// ---------------- K3: Wt[v][h] = bf16(W_out[h][v]), v padded to VPAD with zeros
__global__ __launch_bounds__(256) void wt_transpose_kernel(
    const float* __restrict__ W, unsigned short* __restrict__ Wt)
{
    int hc = blockIdx.x, vc = blockIdx.y;
    int h0 = hc * 64, v0 = vc * 64;
    __shared__ float tile[64][65];
    int tid = threadIdx.x;
    #pragma unroll
    for (int it = 0; it < 16; ++it) {
        int hl = it * 4 + (tid >> 6);
        int vl = tid & 63;
        int v = v0 + vl;
        tile[hl][vl] = (v < V_) ? W[(size_t)(h0 + hl) * V_ + v] : 0.f;
    }
    __syncthreads();
    #pragma unroll
    for (int it = 0; it < 16; ++it) {
        int vl = it * 4 + (tid >> 6);
        int hl = tid & 63;
        __bf16 bv = (__bf16)tile[hl][vl];
        Wt[(size_t)(v0 + vl) * H_ + h0 + hl] = *(unsigned short*)&bv;
    }
}

// ---------------- K4: fused joint kernel, build-X-once structure
// block: 256 thr = 4 waves (2 row-groups x 2 col-groups), rows = 64 (8t x 8u)
// X[64][640] bf16 staged ONCE in 80KB dynamic LDS (16B-chunk XOR swizzle),
// then 9 v-iters x 20 k-steps, barrier-free, B streamed from L2 w/ 2-deep prefetch.
__global__ __launch_bounds__(256) void joint_kernel(
    const __hip_bfloat16* __restrict__ encP,   // [B,T,H] bf16
    const __hip_bfloat16* __restrict__ decP,   // [B,U,H] bf16
    const unsigned short* __restrict__ Wt,     // [VPAD][H] bf16
    const float* __restrict__ b_out,           // [V]
    float* __restrict__ out)                   // [B,T,U,V] f32
{
    extern __shared__ uint4 Xs[];              // [64][80] 16B chunks = 80 KB
    int tu = blockIdx.x;                       // 0..324 (25 t-tiles x 13 u-tiles)
    int b  = blockIdx.y;
    int tt = tu / 13, ut = tu % 13;
    int t0 = tt * 8, u0 = ut * 8;
    int tid = threadIdx.x;

    // ---- build X (once): thread owns row r = tid>>2, chunks (tid&3)*20 .. +20
    {
        int r  = tid >> 2;
        int c0 = (tid & 3) * 20;
        int t = t0 + (r >> 3);
        int u = u0 + (r & 7); if (u > U_ - 1) u = U_ - 1;
        const unsigned short* eR = (const unsigned short*)encP + ((size_t)b * T_ + t) * H_;
        const unsigned short* dR = (const unsigned short*)decP + ((size_t)b * U_ + u) * H_;
        int sw = r & 7;
        #pragma unroll 4
        for (int c = 0; c < 20; ++c) {
            int ch = c0 + c;
            u16x8 e = *(const u16x8*)(eR + ch * 8);
            u16x8 d = *(const u16x8*)(dR + ch * 8);
            bf16x8 x;
            #pragma unroll
            for (int m = 0; m < 8; ++m)
                x[m] = (__bf16)fmaxf(bf2f(e[m]) + bf2f(d[m]), 0.f);
            Xs[r * 80 + (ch ^ sw)] = __builtin_bit_cast(uint4, x);
        }
    }
    __syncthreads();

    int lane = tid & 63, wid = tid >> 6;
    int wr = wid >> 1, wc = wid & 1;           // 2x2 wave grid; wave tile 32 rows x 64 cols
    int lrow = lane & 15, kg = lane >> 4;
    int sw = lrow & 7;

    int arow0 = (wr * 32 + lrow) * 80;         // LDS chunk base, i=0 frag
    int arow1 = (wr * 32 + 16 + lrow) * 80;    // i=1 frag

    #pragma unroll 1
    for (int vi = 0; vi < 9; ++vi) {
        const unsigned short* wp[4];
        #pragma unroll
        for (int j = 0; j < 4; ++j)
            wp[j] = Wt + (size_t)(vi * 128 + wc * 64 + j * 16 + lrow) * H_ + kg * 8;

        f32x4 acc[2][4];
        #pragma unroll
        for (int i = 0; i < 2; ++i)
            #pragma unroll
            for (int j = 0; j < 4; ++j)
                acc[i][j] = (f32x4){0.f, 0.f, 0.f, 0.f};

        bf16x8 bc[4], bn[4];
        #pragma unroll
        for (int j = 0; j < 4; ++j) bc[j] = *(const bf16x8*)(wp[j]);
        #pragma unroll
        for (int j = 0; j < 4; ++j) bn[j] = *(const bf16x8*)(wp[j] + 32);

        #pragma unroll
        for (int ks = 0; ks < 20; ++ks) {
            bf16x8 a0 = __builtin_bit_cast(bf16x8, Xs[arow0 + ((ks * 4 + kg) ^ sw)]);
            bf16x8 a1 = __builtin_bit_cast(bf16x8, Xs[arow1 + ((ks * 4 + kg) ^ sw)]);
            bf16x8 bu[4];
            #pragma unroll
            for (int j = 0; j < 4; ++j) { bu[j] = bc[j]; bc[j] = bn[j]; }
            if (ks < 18) {
                #pragma unroll
                for (int j = 0; j < 4; ++j)
                    bn[j] = *(const bf16x8*)(wp[j] + (ks + 2) * 32);
            }
            #pragma unroll
            for (int j = 0; j < 4; ++j) {
                acc[0][j] = __builtin_amdgcn_mfma_f32_16x16x32_bf16(a0, bu[j], acc[0][j], 0, 0, 0);
                acc[1][j] = __builtin_amdgcn_mfma_f32_16x16x32_bf16(a1, bu[j], acc[1][j], 0, 0, 0);
            }
        }

        // epilogue for this v-iter: D col = lane&15, row = kg*4 + q
        #pragma unroll
        for (int j = 0; j < 4; ++j) {
            int v = vi * 128 + wc * 64 + j * 16 + lrow;
            bool vok = (v < V_);
            float bo = vok ? b_out[v] : 0.f;
            #pragma unroll
            for (int i = 0; i < 2; ++i) {
                #pragma unroll
                for (int q = 0; q < 4; ++q) {
                    int row = wr * 32 + i * 16 + kg * 4 + q;
                    int t = t0 + (row >> 3);
                    int u = u0 + (row & 7);
                    if (vok && u < U_)
                        out[(((size_t)b * T_ + t) * U_ + u) * V_ + v] = acc[i][j][q] + bo;
                }
            }
        }
    }
}

extern "C" void kernel_launch(void* const* d_in, const int* in_sizes, int n_in,
                              void* d_out, int out_size, void* d_ws, size_t ws_size,
                              hipStream_t stream) {
    const float* enc    = (const float*)d_in[0];   // [4,512,200]
    const float* dec    = (const float*)d_in[1];   // [4,640,100]
    const float* W_enc  = (const float*)d_in[2];   // [512,640]
    const float* b_enc  = (const float*)d_in[3];   // [640]
    const float* W_pred = (const float*)d_in[4];   // [640,640]
    const float* b_pred = (const float*)d_in[5];   // [640]
    const float* W_out  = (const float*)d_in[6];   // [640,1025]
    const float* b_out  = (const float*)d_in[7];   // [1025]
    float* out = (float*)d_out;

    char* ws = (char*)d_ws;
    __hip_bfloat16* encP = (__hip_bfloat16*)ws;                       // 4*200*640*2 = 1,024,000
    __hip_bfloat16* decP = (__hip_bfloat16*)(ws + 1024000);           // 4*100*640*2 =   512,000
    unsigned short* Wt   = (unsigned short*)(ws + 1024000 + 512000);  // 1152*640*2  = 1,474,560

    (void)hipFuncSetAttribute((const void*)joint_kernel,
                              hipFuncAttributeMaxDynamicSharedMemorySize, 81920);

    enc_proj_kernel<<<dim3(5, 25, 4), 128, 0, stream>>>(enc, W_enc, b_enc, encP);
    dec_proj_kernel<<<dim3(5, 25, 4), 128, 0, stream>>>(dec, W_pred, b_pred, decP);
    wt_transpose_kernel<<<dim3(10, 18), 256, 0, stream>>>(W_out, Wt);
    joint_kernel<<<dim3(325, 4), 256, 81920, stream>>>(encP, decP, Wt, b_out, out);
}

// Round 4
// 447.082 us; speedup vs baseline: 1.5136x; 1.5136x over previous
//
#include <hip/hip_runtime.h>
#include <hip/hip_bf16.h>

#define B_   4
#define DENC 512
#define T_   200
#define DDEC 640
#define U_   100
#define H_   640
#define V_   1025
#define VPAD 1152

typedef float f32x4 __attribute__((ext_vector_type(4)));
typedef __bf16 bf16x8 __attribute__((ext_vector_type(8)));
typedef unsigned short u16x8 __attribute__((ext_vector_type(8)));

__device__ __forceinline__ float bf2f(unsigned short s) {
    return __uint_as_float(((unsigned)s) << 16);
}

__device__ __forceinline__ unsigned addrelu_pk(unsigned e, unsigned d) {
    float elo = __uint_as_float(e << 16);
    float ehi = __uint_as_float(e & 0xffff0000u);
    float dlo = __uint_as_float(d << 16);
    float dhi = __uint_as_float(d & 0xffff0000u);
    float lo = fmaxf(elo + dlo, 0.f);
    float hi = fmaxf(ehi + dhi, 0.f);
    unsigned r;
    asm("v_cvt_pk_bf16_f32 %0, %1, %2" : "=v"(r) : "v"(lo), "v"(hi));
    return r;
}

__device__ __forceinline__ void gload_lds16(const unsigned short* g, void* l) {
    __builtin_amdgcn_global_load_lds(
        (const __attribute__((address_space(1))) unsigned int*)g,
        (__attribute__((address_space(3))) unsigned int*)l, 16, 0, 0);
}

// ---------------- K1: enc_proj[b,t,h] = bf16( sum_d enc[b,d,t]*W_enc[d,h] + b_enc[h] )
__global__ __launch_bounds__(128) void enc_proj_kernel(
    const float* __restrict__ enc, const float* __restrict__ W,
    const float* __restrict__ bias, __hip_bfloat16* __restrict__ out)
{
    int hc = blockIdx.x, tg = blockIdx.y, b = blockIdx.z;
    int h  = hc * 128 + threadIdx.x;
    int t0 = tg * 8;
    const float* ec = enc + (size_t)b * DENC * T_ + t0;
    const float* Wc = W + h;
    float acc[8] = {0.f,0.f,0.f,0.f,0.f,0.f,0.f,0.f};
    #pragma unroll 8
    for (int d = 0; d < DENC; ++d) {
        float w = Wc[(size_t)d * H_];
        float4 e0 = *(const float4*)(ec + (size_t)d * T_);
        float4 e1 = *(const float4*)(ec + (size_t)d * T_ + 4);
        acc[0] += w * e0.x; acc[1] += w * e0.y; acc[2] += w * e0.z; acc[3] += w * e0.w;
        acc[4] += w * e1.x; acc[5] += w * e1.y; acc[6] += w * e1.z; acc[7] += w * e1.w;
    }
    float bb = bias[h];
    #pragma unroll
    for (int i = 0; i < 8; ++i)
        out[((size_t)b * T_ + t0 + i) * H_ + h] = __float2bfloat16(acc[i] + bb);
}

// ---------------- K2: dec_proj
__global__ __launch_bounds__(128) void dec_proj_kernel(
    const float* __restrict__ dec, const float* __restrict__ W,
    const float* __restrict__ bias, __hip_bfloat16* __restrict__ out)
{
    int hc = blockIdx.x, ug = blockIdx.y, b = blockIdx.z;
    int h  = hc * 128 + threadIdx.x;
    int u0 = ug * 4;
    const float* dc = dec + (size_t)b * DDEC * U_ + u0;
    const float* Wc = W + h;
    float acc[4] = {0.f,0.f,0.f,0.f};
    #pragma unroll 8
    for (int d = 0; d < DDEC; ++d) {
        float w = Wc[(size_t)d * H_];
        float4 e0 = *(const float4*)(dc + (size_t)d * U_);
        acc[0] += w * e0.x; acc[1] += w * e0.y; acc[2] += w * e0.z; acc[3] += w * e0.w;
    }
    float bb = bias[h];
    #pragma unroll
    for (int i = 0; i < 4; ++i)
        out[((size_t)b * U_ + u0 + i) * H_ + h] = __float2bfloat16(acc[i] + bb);
}

// ---------------- K3: Wt[v][h] = bf16(W_out[h][v]) (v padded to VPAD with zeros)
__global__ __launch_bounds__(256) void wt_transpose_kernel(
    const float* __restrict__ W, unsigned short* __restrict__ Wt)
{
    int hc = blockIdx.x, vc = blockIdx.y;
    int h0 = hc * 64, v0 = vc * 64;
    __shared__ float tile[64][65];
    int tid = threadIdx.x;
    #pragma unroll
    for (int it = 0; it < 16; ++it) {
        int hl = it * 4 + (tid >> 6);
        int vl = tid & 63;
        int v = v0 + vl;
        tile[hl][vl] = (v < V_) ? W[(size_t)(h0 + hl) * V_ + v] : 0.f;
    }
    __syncthreads();
    #pragma unroll
    for (int it = 0; it < 16; ++it) {
        int vl = it * 4 + (tid >> 6);
        int hl = tid & 63;
        __bf16 bv = (__bf16)tile[hl][vl];
        Wt[(size_t)(v0 + vl) * H_ + h0 + hl] = *(unsigned short*)&bv;
    }
}

// ---------------- K4: m97-skeleton fused joint GEMM
// 128 rows (16t x 8u) x 128 v-cols, BK=32, 20 K-steps, 4 waves (2x2) of 64x64,
// A built in-LDS from encP+decP (relu+pack), B staged via global_load_lds.
// LDS: A,B double-buffered, chunk-XOR swizzle: phys = kc ^ ((row>>1)&3).
__global__ __launch_bounds__(256) void joint_kernel(
    const unsigned short* __restrict__ encP,   // [B,T,H] bf16
    const unsigned short* __restrict__ decP,   // [B,U,H] bf16
    const unsigned short* __restrict__ Wt,     // [VPAD][H] bf16
    const float* __restrict__ b_out,           // [V]
    float* __restrict__ out)                   // [B,T,U,V] f32
{
    __shared__ uint4 LA[2][128][4];            // 16 KB
    __shared__ uint4 LB[2][128][4];            // 16 KB

    int vi = blockIdx.x;                       // 0..7
    int tu = blockIdx.y;                       // 0..168
    int b  = blockIdx.z;
    int tt = tu / 13, ut = tu % 13;
    int t0 = tt * 16, u0 = ut * 8, vb = vi * 128;
    int tid = threadIdx.x;
    int lane = tid & 63, wid = tid >> 6;
    int wr = wid >> 1, wc = wid & 1;
    int lrow = lane & 15, kg = lane >> 4;

    // ---- A-build mapping: thread owns row r, k-half kh (16 elems = chunks 2kh,2kh+1)
    int r  = tid >> 1, kh = tid & 1;
    int ta = t0 + (r >> 3); if (ta > T_ - 1) ta = T_ - 1;
    int ua = u0 + (r & 7);  if (ua > U_ - 1) ua = U_ - 1;
    const unsigned short* eR = encP + ((size_t)b * T_ + ta) * H_ + kh * 16;
    const unsigned short* dR = decP + ((size_t)b * U_ + ua) * H_ + kh * 16;
    int fA = (r >> 1) & 3;

    // ---- B gload mapping: wave `wid` stages cols 32*wid..32*wid+31; 2 instrs of 16 cols
    int cB0 = 32 * wid + (lane >> 2);
    int cB1 = cB0 + 16;
    int pcB = lane & 3;
    const unsigned short* gB0 = Wt + (size_t)(vb + cB0) * H_ + (size_t)((pcB ^ ((cB0 >> 1) & 3)) * 8);
    const unsigned short* gB1 = Wt + (size_t)(vb + cB1) * H_ + (size_t)((pcB ^ ((cB1 >> 1) & 3)) * 8);

    f32x4 acc[4][4];
    #pragma unroll
    for (int i = 0; i < 4; ++i)
        #pragma unroll
        for (int j = 0; j < 4; ++j)
            acc[i][j] = (f32x4){0.f, 0.f, 0.f, 0.f};

    // ---- prologue: stage k-step 0 into buf 0
    {
        uint4 E0 = *(const uint4*)(eR), E1 = *(const uint4*)(eR + 8);
        uint4 D0 = *(const uint4*)(dR), D1 = *(const uint4*)(dR + 8);
        uint4 x0, x1;
        x0.x = addrelu_pk(E0.x, D0.x); x0.y = addrelu_pk(E0.y, D0.y);
        x0.z = addrelu_pk(E0.z, D0.z); x0.w = addrelu_pk(E0.w, D0.w);
        x1.x = addrelu_pk(E1.x, D1.x); x1.y = addrelu_pk(E1.y, D1.y);
        x1.z = addrelu_pk(E1.z, D1.z); x1.w = addrelu_pk(E1.w, D1.w);
        LA[0][r][(2 * kh) ^ fA]     = x0;
        LA[0][r][(2 * kh + 1) ^ fA] = x1;
        gload_lds16(gB0, &LB[0][32 * wid][0]);
        gload_lds16(gB1, &LB[0][32 * wid + 16][0]);
    }
    __syncthreads();

    // ---- main K loop: 20 steps of K=32
    #pragma unroll 2
    for (int kt = 0; kt < 20; ++kt) {
        int cur = kt & 1;
        uint4 E0n, E1n, D0n, D1n;
        if (kt < 19) {
            const unsigned short* e2 = eR + (kt + 1) * 32;
            const unsigned short* d2 = dR + (kt + 1) * 32;
            E0n = *(const uint4*)(e2); E1n = *(const uint4*)(e2 + 8);
            D0n = *(const uint4*)(d2); D1n = *(const uint4*)(d2 + 8);
            gload_lds16(gB0 + (kt + 1) * 32, &LB[cur ^ 1][32 * wid][0]);
            gload_lds16(gB1 + (kt + 1) * 32, &LB[cur ^ 1][32 * wid + 16][0]);
        }
        bf16x8 a[4], bq[4];
        #pragma unroll
        for (int i = 0; i < 4; ++i) {
            int row = wr * 64 + i * 16 + lrow;
            a[i] = __builtin_bit_cast(bf16x8, LA[cur][row][kg ^ ((row >> 1) & 3)]);
        }
        #pragma unroll
        for (int j = 0; j < 4; ++j) {
            int col = wc * 64 + j * 16 + lrow;
            bq[j] = __builtin_bit_cast(bf16x8, LB[cur][col][kg ^ ((col >> 1) & 3)]);
        }
        #pragma unroll
        for (int i = 0; i < 4; ++i)
            #pragma unroll
            for (int j = 0; j < 4; ++j)
                acc[i][j] = __builtin_amdgcn_mfma_f32_16x16x32_bf16(a[i], bq[j], acc[i][j], 0, 0, 0);
        if (kt < 19) {
            uint4 x0, x1;
            x0.x = addrelu_pk(E0n.x, D0n.x); x0.y = addrelu_pk(E0n.y, D0n.y);
            x0.z = addrelu_pk(E0n.z, D0n.z); x0.w = addrelu_pk(E0n.w, D0n.w);
            x1.x = addrelu_pk(E1n.x, D1n.x); x1.y = addrelu_pk(E1n.y, D1n.y);
            x1.z = addrelu_pk(E1n.z, D1n.z); x1.w = addrelu_pk(E1n.w, D1n.w);
            LA[cur ^ 1][r][(2 * kh) ^ fA]     = x0;
            LA[cur ^ 1][r][(2 * kh + 1) ^ fA] = x1;
        }
        __syncthreads();
    }

    // ---- epilogue: D col = lane&15, row = kg*4 + q   (v < 1024 always: no v check)
    #pragma unroll
    for (int j = 0; j < 4; ++j) {
        int v = vb + wc * 64 + j * 16 + lrow;
        float bo = b_out[v];
        #pragma unroll
        for (int i = 0; i < 4; ++i) {
            #pragma unroll
            for (int q = 0; q < 4; ++q) {
                int row = wr * 64 + i * 16 + kg * 4 + q;
                int t = t0 + (row >> 3);
                int u = u0 + (row & 7);
                if (t < T_ && u < U_)
                    out[(((size_t)b * T_ + t) * U_ + u) * V_ + v] = acc[i][j][q] + bo;
            }
        }
    }
}

// ---------------- K5: last output column v=1024 (plain dot products)
__global__ __launch_bounds__(256) void lastcol_kernel(
    const unsigned short* __restrict__ encP, const unsigned short* __restrict__ decP,
    const unsigned short* __restrict__ Wt, const float* __restrict__ b_out,
    float* __restrict__ out)
{
    int idx = blockIdx.x * 256 + threadIdx.x;
    if (idx >= B_ * T_ * U_) return;
    int u = idx % U_;
    int t = (idx / U_) % T_;
    int b = idx / (U_ * T_);
    const u16x8* e = (const u16x8*)(encP + ((size_t)b * T_ + t) * H_);
    const u16x8* d = (const u16x8*)(decP + ((size_t)b * U_ + u) * H_);
    const u16x8* w = (const u16x8*)(Wt + (size_t)1024 * H_);
    float acc = 0.f;
    for (int c = 0; c < H_ / 8; ++c) {
        u16x8 ev = e[c], dv = d[c], wv = w[c];
        #pragma unroll
        for (int m = 0; m < 8; ++m)
            acc += fmaxf(bf2f(ev[m]) + bf2f(dv[m]), 0.f) * bf2f(wv[m]);
    }
    out[((size_t)(b * T_ + t) * U_ + u) * V_ + 1024] = acc + b_out[1024];
}

extern "C" void kernel_launch(void* const* d_in, const int* in_sizes, int n_in,
                              void* d_out, int out_size, void* d_ws, size_t ws_size,
                              hipStream_t stream) {
    const float* enc    = (const float*)d_in[0];
    const float* dec    = (const float*)d_in[1];
    const float* W_enc  = (const float*)d_in[2];
    const float* b_enc  = (const float*)d_in[3];
    const float* W_pred = (const float*)d_in[4];
    const float* b_pred = (const float*)d_in[5];
    const float* W_out  = (const float*)d_in[6];
    const float* b_out  = (const float*)d_in[7];
    float* out = (float*)d_out;

    char* ws = (char*)d_ws;
    __hip_bfloat16* encP = (__hip_bfloat16*)ws;                       // 1,024,000 B
    __hip_bfloat16* decP = (__hip_bfloat16*)(ws + 1024000);           //   512,000 B
    unsigned short* Wt   = (unsigned short*)(ws + 1024000 + 512000);  // 1,474,560 B

    enc_proj_kernel<<<dim3(5, 25, 4), 128, 0, stream>>>(enc, W_enc, b_enc, encP);
    dec_proj_kernel<<<dim3(5, 25, 4), 128, 0, stream>>>(dec, W_pred, b_pred, decP);
    wt_transpose_kernel<<<dim3(10, 18), 256, 0, stream>>>(W_out, Wt);
    joint_kernel<<<dim3(8, 169, 4), 256, 0, stream>>>(
        (const unsigned short*)encP, (const unsigned short*)decP, Wt, b_out, out);
    lastcol_kernel<<<dim3((B_ * T_ * U_ + 255) / 256), 256, 0, stream>>>(
        (const unsigned short*)encP, (const unsigned short*)decP, Wt, b_out, out);
}

// Round 8
// 391.989 us; speedup vs baseline: 1.7264x; 1.1405x over previous
//
#include <hip/hip_runtime.h>
#include <hip/hip_bf16.h>

#define B_   4
#define DENC 512
#define T_   200
#define DDEC 640
#define U_   100
#define H_   640
#define V_   1025
#define VPAD 1152

typedef float f32x4 __attribute__((ext_vector_type(4)));
typedef __bf16 bf16x8 __attribute__((ext_vector_type(8)));
typedef unsigned short u16x8 __attribute__((ext_vector_type(8)));

__device__ __forceinline__ float bf2f(unsigned short s) {
    return __uint_as_float(((unsigned)s) << 16);
}

__device__ __forceinline__ unsigned addrelu_pk(unsigned e, unsigned d) {
    float elo = __uint_as_float(e << 16);
    float ehi = __uint_as_float(e & 0xffff0000u);
    float dlo = __uint_as_float(d << 16);
    float dhi = __uint_as_float(d & 0xffff0000u);
    float lo = fmaxf(elo + dlo, 0.f);
    float hi = fmaxf(ehi + dhi, 0.f);
    unsigned r;
    asm("v_cvt_pk_bf16_f32 %0, %1, %2" : "=v"(r) : "v"(lo), "v"(hi));
    return r;
}

__device__ __forceinline__ void gload_lds16(const void* g, void* l) {
    __builtin_amdgcn_global_load_lds(
        (const __attribute__((address_space(1))) unsigned int*)g,
        (__attribute__((address_space(3))) unsigned int*)l, 16, 0, 0);
}

// ---------------- K1: enc_proj[b,t,h] = bf16( sum_d enc[b,d,t]*W_enc[d,h] + b_enc[h] )
__global__ __launch_bounds__(128) void enc_proj_kernel(
    const float* __restrict__ enc, const float* __restrict__ W,
    const float* __restrict__ bias, __hip_bfloat16* __restrict__ out)
{
    int hc = blockIdx.x, tg = blockIdx.y, b = blockIdx.z;
    int h  = hc * 128 + threadIdx.x;
    int t0 = tg * 8;
    const float* ec = enc + (size_t)b * DENC * T_ + t0;
    const float* Wc = W + h;
    float acc[8] = {0.f,0.f,0.f,0.f,0.f,0.f,0.f,0.f};
    #pragma unroll 8
    for (int d = 0; d < DENC; ++d) {
        float w = Wc[(size_t)d * H_];
        float4 e0 = *(const float4*)(ec + (size_t)d * T_);
        float4 e1 = *(const float4*)(ec + (size_t)d * T_ + 4);
        acc[0] += w * e0.x; acc[1] += w * e0.y; acc[2] += w * e0.z; acc[3] += w * e0.w;
        acc[4] += w * e1.x; acc[5] += w * e1.y; acc[6] += w * e1.z; acc[7] += w * e1.w;
    }
    float bb = bias[h];
    #pragma unroll
    for (int i = 0; i < 8; ++i)
        out[((size_t)b * T_ + t0 + i) * H_ + h] = __float2bfloat16(acc[i] + bb);
}

// ---------------- K2: dec_proj
__global__ __launch_bounds__(128) void dec_proj_kernel(
    const float* __restrict__ dec, const float* __restrict__ W,
    const float* __restrict__ bias, __hip_bfloat16* __restrict__ out)
{
    int hc = blockIdx.x, ug = blockIdx.y, b = blockIdx.z;
    int h  = hc * 128 + threadIdx.x;
    int u0 = ug * 4;
    const float* dc = dec + (size_t)b * DDEC * U_ + u0;
    const float* Wc = W + h;
    float acc[4] = {0.f,0.f,0.f,0.f};
    #pragma unroll 8
    for (int d = 0; d < DDEC; ++d) {
        float w = Wc[(size_t)d * H_];
        float4 e0 = *(const float4*)(dc + (size_t)d * U_);
        acc[0] += w * e0.x; acc[1] += w * e0.y; acc[2] += w * e0.z; acc[3] += w * e0.w;
    }
    float bb = bias[h];
    #pragma unroll
    for (int i = 0; i < 4; ++i)
        out[((size_t)b * U_ + u0 + i) * H_ + h] = __float2bfloat16(acc[i] + bb);
}

// ---------------- K3: Wt[v][h] = bf16(W_out[h][v]) (v padded to VPAD with zeros)
__global__ __launch_bounds__(256) void wt_transpose_kernel(
    const float* __restrict__ W, unsigned short* __restrict__ Wt)
{
    int hc = blockIdx.x, vc = blockIdx.y;
    int h0 = hc * 64, v0 = vc * 64;
    __shared__ float tile[64][65];
    int tid = threadIdx.x;
    #pragma unroll
    for (int it = 0; it < 16; ++it) {
        int hl = it * 4 + (tid >> 6);
        int vl = tid & 63;
        int v = v0 + vl;
        tile[hl][vl] = (v < V_) ? W[(size_t)(h0 + hl) * V_ + v] : 0.f;
    }
    __syncthreads();
    #pragma unroll
    for (int it = 0; it < 16; ++it) {
        int vl = it * 4 + (tid >> 6);
        int hl = tid & 63;
        __bf16 bv = (__bf16)tile[hl][vl];
        Wt[(size_t)(v0 + vl) * H_ + h0 + hl] = *(unsigned short*)&bv;
    }
}

// ---------------- K4: round-4 skeleton, widened to 64 rows x 256 v-cols
// 256 thr = 4 waves (1x4), wave = 64 rows x 64 cols, acc[4][4], BK=32, 20 K-steps.
// A built in-LDS from encP+decP (relu+pack), B staged via global_load_lds.
// Both LDS tiles double-buffered; chunk-XOR swizzle phys = kc ^ ((row>>1)&3).
__global__ __launch_bounds__(256) void joint_kernel(
    const unsigned short* __restrict__ encP,   // [B,T,H] bf16
    const unsigned short* __restrict__ decP,   // [B,U,H] bf16
    const unsigned short* __restrict__ Wt,     // [VPAD][H] bf16
    const float* __restrict__ b_out,           // [V]
    float* __restrict__ out)                   // [B,T,U,V] f32
{
    __shared__ uint4 LA[2][64][4];             // 8 KB
    __shared__ uint4 LB[2][256][4];            // 32 KB

    int vi = blockIdx.x;                       // 0..3
    int tu = blockIdx.y;                       // 0..324
    int b  = blockIdx.z;
    int tt = tu / 13, ut = tu % 13;
    int t0 = tt * 8, u0 = ut * 8, vb = vi * 256;
    int tid = threadIdx.x;
    int lane = tid & 63, w = tid >> 6;         // w = wave = col-group 0..3
    int lrow = lane & 15, kg = lane >> 4;

    // ---- A-build mapping: thread owns row r (0..63), chunk kc (0..3)
    int r  = tid >> 2, kc = tid & 3;
    int ta = t0 + (r >> 3);                    // always < 200 (t exact)
    int ua = u0 + (r & 7); if (ua > U_ - 1) ua = U_ - 1;
    const unsigned short* eR = encP + ((size_t)b * T_ + ta) * H_ + kc * 8;
    const unsigned short* dR = decP + ((size_t)b * U_ + ua) * H_ + kc * 8;
    int fA = (r >> 1) & 3;

    // ---- B gload mapping: wave w stages local cols 64w..64w+63; 4 instrs of 16 cols
    int pcB = lane & 3;
    const unsigned short* gB[4];
    #pragma unroll
    for (int m = 0; m < 4; ++m) {
        int cl = w * 64 + m * 16 + (lane >> 2);
        gB[m] = Wt + (size_t)(vb + cl) * H_ + (pcB ^ ((cl >> 1) & 3)) * 8;
    }

    f32x4 acc[4][4];
    #pragma unroll
    for (int i = 0; i < 4; ++i)
        #pragma unroll
        for (int j = 0; j < 4; ++j)
            acc[i][j] = (f32x4){0.f, 0.f, 0.f, 0.f};

    // ---- prologue: stage k-step 0 into buf 0
    {
        uint4 E = *(const uint4*)(eR);
        uint4 D = *(const uint4*)(dR);
        uint4 x;
        x.x = addrelu_pk(E.x, D.x); x.y = addrelu_pk(E.y, D.y);
        x.z = addrelu_pk(E.z, D.z); x.w = addrelu_pk(E.w, D.w);
        LA[0][r][kc ^ fA] = x;
        #pragma unroll
        for (int m = 0; m < 4; ++m)
            gload_lds16(gB[m], &LB[0][w * 64 + m * 16][0]);
    }
    __syncthreads();

    // ---- main K loop: 20 steps of K=32
    #pragma unroll 2
    for (int kt = 0; kt < 20; ++kt) {
        int cur = kt & 1;
        uint4 En, Dn;
        if (kt < 19) {
            En = *(const uint4*)(eR + (kt + 1) * 32);
            Dn = *(const uint4*)(dR + (kt + 1) * 32);
            #pragma unroll
            for (int m = 0; m < 4; ++m)
                gload_lds16(gB[m] + (kt + 1) * 32, &LB[cur ^ 1][w * 64 + m * 16][0]);
        }
        bf16x8 a[4], bq[4];
        #pragma unroll
        for (int i = 0; i < 4; ++i) {
            int row = i * 16 + lrow;
            a[i] = __builtin_bit_cast(bf16x8, LA[cur][row][kg ^ ((row >> 1) & 3)]);
        }
        #pragma unroll
        for (int j = 0; j < 4; ++j) {
            int col = w * 64 + j * 16 + lrow;
            bq[j] = __builtin_bit_cast(bf16x8, LB[cur][col][kg ^ ((col >> 1) & 3)]);
        }
        #pragma unroll
        for (int i = 0; i < 4; ++i)
            #pragma unroll
            for (int j = 0; j < 4; ++j)
                acc[i][j] = __builtin_amdgcn_mfma_f32_16x16x32_bf16(a[i], bq[j], acc[i][j], 0, 0, 0);
        if (kt < 19) {
            uint4 x;
            x.x = addrelu_pk(En.x, Dn.x); x.y = addrelu_pk(En.y, Dn.y);
            x.z = addrelu_pk(En.z, Dn.z); x.w = addrelu_pk(En.w, Dn.w);
            LA[cur ^ 1][r][kc ^ fA] = x;
        }
        __syncthreads();
    }

    // ---- epilogue: D col = lane&15, row = kg*4 + q   (v < 1024 always)
    #pragma unroll
    for (int j = 0; j < 4; ++j) {
        int v = vb + w * 64 + j * 16 + lrow;
        float bo = b_out[v];
        #pragma unroll
        for (int i = 0; i < 4; ++i) {
            #pragma unroll
            for (int q = 0; q < 4; ++q) {
                int row = i * 16 + kg * 4 + q;
                int t = t0 + (row >> 3);
                int u = u0 + (row & 7);
                if (u < U_)
                    out[(((size_t)b * T_ + t) * U_ + u) * V_ + v] = acc[i][j][q] + bo;
            }
        }
    }
}

// ---------------- K5: last output column v=1024 (plain dot products)
__global__ __launch_bounds__(256) void lastcol_kernel(
    const unsigned short* __restrict__ encP, const unsigned short* __restrict__ decP,
    const unsigned short* __restrict__ Wt, const float* __restrict__ b_out,
    float* __restrict__ out)
{
    int idx = blockIdx.x * 256 + threadIdx.x;
    if (idx >= B_ * T_ * U_) return;
    int u = idx % U_;
    int t = (idx / U_) % T_;
    int b = idx / (U_ * T_);
    const u16x8* e = (const u16x8*)(encP + ((size_t)b * T_ + t) * H_);
    const u16x8* d = (const u16x8*)(decP + ((size_t)b * U_ + u) * H_);
    const u16x8* wv = (const u16x8*)(Wt + (size_t)1024 * H_);
    float acc = 0.f;
    for (int c = 0; c < H_ / 8; ++c) {
        u16x8 ev = e[c], dv = d[c], wq = wv[c];
        #pragma unroll
        for (int m = 0; m < 8; ++m)
            acc += fmaxf(bf2f(ev[m]) + bf2f(dv[m]), 0.f) * bf2f(wq[m]);
    }
    out[((size_t)(b * T_ + t) * U_ + u) * V_ + 1024] = acc + b_out[1024];
}

extern "C" void kernel_launch(void* const* d_in, const int* in_sizes, int n_in,
                              void* d_out, int out_size, void* d_ws, size_t ws_size,
                              hipStream_t stream) {
    const float* enc    = (const float*)d_in[0];
    const float* dec    = (const float*)d_in[1];
    const float* W_enc  = (const float*)d_in[2];
    const float* b_enc  = (const float*)d_in[3];
    const float* W_pred = (const float*)d_in[4];
    const float* b_pred = (const float*)d_in[5];
    const float* W_out  = (const float*)d_in[6];
    const float* b_out  = (const float*)d_in[7];
    float* out = (float*)d_out;

    char* ws = (char*)d_ws;
    __hip_bfloat16* encP = (__hip_bfloat16*)ws;                       // 1,024,000 B
    __hip_bfloat16* decP = (__hip_bfloat16*)(ws + 1024000);           //   512,000 B
    unsigned short* Wt   = (unsigned short*)(ws + 1024000 + 512000);  // 1,474,560 B

    enc_proj_kernel<<<dim3(5, 25, 4), 128, 0, stream>>>(enc, W_enc, b_enc, encP);
    dec_proj_kernel<<<dim3(5, 25, 4), 128, 0, stream>>>(dec, W_pred, b_pred, decP);
    wt_transpose_kernel<<<dim3(10, 18), 256, 0, stream>>>(W_out, Wt);
    joint_kernel<<<dim3(4, 325, 4), 256, 0, stream>>>(
        (const unsigned short*)encP, (const unsigned short*)decP, Wt, b_out, out);
    lastcol_kernel<<<dim3((B_ * T_ * U_ + 255) / 256), 256, 0, stream>>>(
        (const unsigned short*)encP, (const unsigned short*)decP, Wt, b_out, out);
}